// Round 11
// baseline (318.685 us; speedup 1.0000x reference)
//
#include <hip/hip_runtime.h>
#include <hip/hip_bf16.h>
#include <cmath>

#define USER_NUM 52643
#define ITEM_NUM 91599
#define NNODE (USER_NUM + ITEM_NUM)   // 144242
#define DDIM 64
#define NBUCK 564                     // ceil(NNODE/256)
#define EPB 8192                      // edges per staging block
#define BCAP 8192                     // max edges per bucket
#define FSCALE 512.0f                 // fp8 table scale

typedef unsigned int uint32;
typedef unsigned short ushort;

using bf16x8 = __attribute__((ext_vector_type(8))) short;
using f32x4  = __attribute__((ext_vector_type(4))) float;
using f32x2  = __attribute__((ext_vector_type(2))) float;

__device__ __forceinline__ uint32 f2bf(float f) {
    uint32 u = __float_as_uint(f);
    u += 0x7fffu + ((u >> 16) & 1u);   // round-to-nearest-even
    return u >> 16;
}
__device__ __forceinline__ uint32 packbf(float lo, float hi) {
    return (f2bf(hi) << 16) | f2bf(lo);
}

// HW decode: 2 fp8(e4m3fn) bytes -> 2 f32
__device__ __forceinline__ f32x2 fp8x2_to_f32(uint32 u) {
#if __has_builtin(__builtin_amdgcn_cvt_pk_f32_fp8)
    return __builtin_amdgcn_cvt_pk_f32_fp8((int)u, false);
#else
    f32x2 r;
    asm("v_cvt_pk_f32_fp8 %0, %1" : "=v"(r) : "v"(u));
    return r;
#endif
}

// cold-path f32 -> e4m3fn encode (RNE, clamp at 448)
__device__ uint32 f2fp8(float f) {
    float a = fabsf(f);
    uint32 s = (f < 0.f) ? 0x80u : 0u;
    if (!(a > 0.f)) return s;
    if (a >= 448.f) return s | 0x7Eu;
    int e = (int)((__float_as_uint(a) >> 23) & 0xFF) - 127;
    if (e < -6) e = -6;
    float q = exp2f((float)(e - 3));
    float r = rintf(a / q) * q;        // RNE quantize
    if (r == 0.f) return s;
    int e2 = (int)((__float_as_uint(r) >> 23) & 0xFF) - 127;
    uint32 enc;
    if (e2 < -6) enc = (uint32)rintf(r * 512.f);                       // subnormal
    else enc = ((uint32)(e2 + 7) << 3) | ((uint32)rintf(r / exp2f((float)(e2 - 3))) - 8u);
    return s | enc;
}

// ---------------- small utility kernels ----------------

__global__ void init_loss_kernel(float* __restrict__ out, int loss_idx) {
    if (threadIdx.x == 0) out[loss_idx] = 0.0f;
}

// ---------------- bucketed CSR build (all global writes dense) ----------------

__global__ __launch_bounds__(1024) void bucket_count_kernel(
    const int* __restrict__ rows, int* __restrict__ blkcnt, int E)
{
    __shared__ int cnt[NBUCK];
    int t = threadIdx.x;
    for (int i = t; i < NBUCK; i += 1024) cnt[i] = 0;
    __syncthreads();
    int base = blockIdx.x * EPB;
    for (int i = t; i < EPB; i += 1024) {
        int e = base + i;
        if (e < E) atomicAdd(&cnt[rows[e] >> 8], 1);
    }
    __syncthreads();
    for (int i = t; i < NBUCK; i += 1024) blkcnt[blockIdx.x * NBUCK + i] = cnt[i];
}

__global__ __launch_bounds__(256) void bucket_block_scan_kernel(
    int* __restrict__ blkcnt, int* __restrict__ totals, int nblocks)
{
    __shared__ int wsum[4];
    int b = blockIdx.x, t = threadIdx.x;
    int lane = t & 63, wid = t >> 6;
    int c = (t < nblocks) ? blkcnt[t * NBUCK + b] : 0;
    int v = c;
    #pragma unroll
    for (int d = 1; d < 64; d <<= 1) {
        int src = (lane >= d) ? (lane - d) : lane;
        int tmp = __shfl(v, src);
        v += (lane >= d) ? tmp : 0;
    }
    if (lane == 63) wsum[wid] = v;
    __syncthreads();
    int woff = 0;
    for (int w = 0; w < wid; ++w) woff += wsum[w];
    int excl = woff + v - c;
    if (t < nblocks) blkcnt[t * NBUCK + b] = excl;
    if (t == 255) totals[b] = excl + c;
}

__global__ __launch_bounds__(1024) void bucket_off_kernel(
    const int* __restrict__ totals, int* __restrict__ bucket_off,
    int* __restrict__ row_ptr, int E)
{
    __shared__ int s[1024];
    int t = threadIdx.x;
    int v = (t < NBUCK) ? totals[t] : 0;
    s[t] = v;
    __syncthreads();
    #pragma unroll
    for (int d = 1; d < 1024; d <<= 1) {
        int add = (t >= d) ? s[t - d] : 0;
        __syncthreads();
        s[t] += add;
        __syncthreads();
    }
    if (t < NBUCK) bucket_off[t] = s[t] - v;
    if (t == 0) { bucket_off[NBUCK] = E; row_ptr[NNODE] = E; }
}

__global__ __launch_bounds__(1024) void stage_kernel(
    const int* __restrict__ rows, const int* __restrict__ cols,
    const int* __restrict__ blkcnt, const int* __restrict__ bucket_off,
    uint32* __restrict__ staged, int E)
{
    __shared__ int cnt[NBUCK];
    __shared__ int basel[NBUCK];
    int t = threadIdx.x;
    for (int i = t; i < NBUCK; i += 1024) {
        cnt[i] = 0;
        basel[i] = bucket_off[i] + blkcnt[blockIdx.x * NBUCK + i];
    }
    __syncthreads();
    int base = blockIdx.x * EPB;
    for (int i = t; i < EPB; i += 1024) {
        int e = base + i;
        if (e < E) {
            int r = rows[e];
            int bkt = r >> 8;
            int rank = atomicAdd(&cnt[bkt], 1);
            staged[basel[bkt] + rank] = ((uint32)(r & 255) << 18) | (uint32)cols[e];
        }
    }
}

__global__ __launch_bounds__(256) void build_kernel(
    const uint32* __restrict__ staged, const int* __restrict__ bucket_off,
    int* __restrict__ row_ptr, int* __restrict__ csr_col,
    float* __restrict__ dinv, float* __restrict__ wout, float* __restrict__ sback)
{
    __shared__ int cnt[256];
    __shared__ int off[256];
    __shared__ int wsum[4];
    __shared__ int colbuf[BCAP];
    int b = blockIdx.x, t = threadIdx.x;
    int lane = t & 63, wid = t >> 6;
    int eoff = bucket_off[b];
    int ecnt = bucket_off[b + 1] - eoff;

    cnt[t] = 0;
    __syncthreads();
    for (int i = t; i < ecnt; i += 256) atomicAdd(&cnt[staged[eoff + i] >> 18], 1);
    __syncthreads();

    int c = cnt[t];
    int v = c;
    #pragma unroll
    for (int d = 1; d < 64; d <<= 1) {
        int src = (lane >= d) ? (lane - d) : lane;
        int tmp = __shfl(v, src);
        v += (lane >= d) ? tmp : 0;
    }
    if (lane == 63) wsum[wid] = v;
    __syncthreads();
    int woff = 0;
    for (int w = 0; w < wid; ++w) woff += wsum[w];
    int excl = woff + v - c;
    off[t] = excl;

    int node = b * 256 + t;
    if (node < NNODE) {
        row_ptr[node] = eoff + excl;
        float df = (float)c;
        float dv = (c > 0) ? (1.0f / sqrtf(df)) : 0.0f;
        dinv[node]  = dv;
        wout[node]  = (c > 0) ? dv : 1.0f;
        sback[node] = (c > 0) ? sqrtf(df) : 1.0f;
    }
    __syncthreads();
    cnt[t] = 0;
    __syncthreads();
    for (int i = t; i < ecnt; i += 256) {
        uint32 w = staged[eoff + i];
        int rl = w >> 18;
        int rank = atomicAdd(&cnt[rl], 1);
        colbuf[off[rl] + rank] = (int)(w & 0x3FFFFu);
    }
    __syncthreads();
    for (int i = t; i < ecnt; i += 256) csr_col[eoff + i] = colbuf[i];
}

// edge records: (col, sback[col]) coalesced — removes random sback gather from gnn
__global__ void edge2_kernel(const int* __restrict__ csr_col, const float* __restrict__ sback,
                             uint2* __restrict__ edge2, int E) {
    int e = blockIdx.x * 256 + threadIdx.x;
    if (e < E) {
        int c = csr_col[e];
        edge2[e] = make_uint2((uint32)c, __float_as_uint(sback[c]));
    }
}

// pack layer-1 tables: bf16 pair table (identity/score) + fp8 table (gathers, xFSCALE).
// Zero dummy row NNODE in all gather-reachable tables.
__global__ void pack1_kernel(const float* __restrict__ eu, const float* __restrict__ ei,
                             const float* __restrict__ wout,
                             uint32* __restrict__ b1tab, uint32* __restrict__ b2tab,
                             ushort* __restrict__ f1tab, ushort* __restrict__ f2tab) {
    int t = blockIdx.x * 256 + threadIdx.x;     // t = n*32 + d2
    int n = t >> 5, d2 = t & 31;
    if (n > NNODE) return;
    if (n == NNODE) { b1tab[t] = 0; b2tab[t] = 0; f1tab[t] = 0; f2tab[t] = 0; return; }
    const float* xp = (n < USER_NUM) ? (eu + ((size_t)n << 6))
                                     : (ei + (((size_t)n - USER_NUM) << 6));
    float2 x2 = *(const float2*)(xp + 2 * d2);
    float wv = wout[n];
    float y0 = wv * x2.x, y1 = wv * x2.y;
    b1tab[t] = packbf(y0, y1);
    f1tab[t] = (ushort)(f2fp8(FSCALE * y0) | (f2fp8(FSCALE * y1) << 8));
    (void)d2;
}

// ---------------- fused GNN layer ----------------
// Gather: dual-row chains; per edge: uniform edge2 load (L1 broadcast, no shuffles)
// -> fp8 2B gather (64B line per edge) -> HW cvt -> accumulate. p2 via si from edge2.
// Identity from bf16 table (coalesced). Epilogue: MFMA; writes bf16 (+ fp8 if oftab).

__global__ __launch_bounds__(256, 8) void gnn_layer_kernel(
    const ushort* __restrict__ ftab, const uint32* __restrict__ btab,
    const uint2* __restrict__ edge2, const int* __restrict__ row_ptr,
    const float* __restrict__ sback, const float* __restrict__ dinv,
    const float* __restrict__ wout,
    const float* __restrict__ W, const float* __restrict__ b,
    const float* __restrict__ Wi, const float* __restrict__ bi,
    uint32* __restrict__ obtab, ushort* __restrict__ oftab)
{
    __shared__ unsigned short P1s[64 * 64];   // [row][dim] bf16, byte-col ^ ((row&7)<<4)
    __shared__ unsigned short P2s[64 * 64];

    int tid = threadIdx.x;
    int lane = tid & 63;
    int wid = tid >> 6;
    int h = lane >> 5;        // edge parity
    int d2 = lane & 31;       // dim-pair index
    int base = blockIdx.x * 64;
    int wbase = base + wid * 16;

    int rp = 0;
    if (lane <= 16) rp = row_ptr[min(wbase + lane, NNODE)];

    const float invS  = 1.0f / FSCALE;
    const float invS2 = 1.0f / (FSCALE * FSCALE);

    // ---- gather phase: 16 rows per wave, interleaved pairs ----
    for (int i = 0; i < 16; i += 2) {
        int e0a = __shfl(rp, i);
        int e1a = __shfl(rp, i + 1);
        int e1b = __shfl(rp, i + 2);
        int e0b = e1a;

        float aA0 = 0.f, aB0 = 0.f, aC0 = 0.f, aD0 = 0.f;
        float aA1 = 0.f, aB1 = 0.f, aC1 = 0.f, aD1 = 0.f;

        int eba = e0a, ebb = e0b;
        while (eba < e1a || ebb < e1b) {
            int nna = e1a - eba; nna = (nna < 0) ? 0 : ((nna > 64) ? 64 : nna);
            int nnb = e1b - ebb; nnb = (nnb < 0) ? 0 : ((nnb > 64) ? 64 : nnb);
            int nn = max(nna, nnb);
            for (int k = 0; k < nn; k += 8) {
                f32x2 fa[4], fb[4];
                float sa[4], sb2[4];
                #pragma unroll
                for (int u = 0; u < 4; ++u) {
                    int ea = eba + k + 2 * u + h;
                    int eb = ebb + k + 2 * u + h;
                    bool va = ea < e1a;
                    bool vb = eb < e1b;
                    uint2 eda = edge2[va ? ea : 0];     // uniform per half-wave: L1 broadcast
                    uint2 edb = edge2[vb ? eb : 0];
                    int ca = va ? (int)eda.x : NNODE;   // dummy row NNODE = zeros
                    int cb = vb ? (int)edb.x : NNODE;
                    sa[u]  = va ? __uint_as_float(eda.y) : 0.f;
                    sb2[u] = vb ? __uint_as_float(edb.y) : 0.f;
                    uint32 ga = (uint32)ftab[(size_t)ca * 32 + d2];  // 2B fp8-pair gather
                    uint32 gb = (uint32)ftab[(size_t)cb * 32 + d2];
                    fa[u] = fp8x2_to_f32(ga);
                    fb[u] = fp8x2_to_f32(gb);
                }
                #pragma unroll
                for (int u = 0; u < 4; ++u) {
                    aA0 += fa[u].x; aB0 += fa[u].y;
                    aC0 = fmaf(fa[u].x * fa[u].x, sa[u], aC0);
                    aD0 = fmaf(fa[u].y * fa[u].y, sa[u], aD0);
                    aA1 += fb[u].x; aB1 += fb[u].y;
                    aC1 = fmaf(fb[u].x * fb[u].x, sb2[u], aC1);
                    aD1 = fmaf(fb[u].y * fb[u].y, sb2[u], aD1);
                }
            }
            eba += 64; ebb += 64;
        }

        // combine edge parities
        aA0 += __shfl_xor(aA0, 32); aB0 += __shfl_xor(aB0, 32);
        aC0 += __shfl_xor(aC0, 32); aD0 += __shfl_xor(aD0, 32);
        aA1 += __shfl_xor(aA1, 32); aB1 += __shfl_xor(aB1, 32);
        aC1 += __shfl_xor(aC1, 32); aD1 += __shfl_xor(aD1, 32);

        #pragma unroll
        for (int s = 0; s < 2; ++s) {
            int row = wbase + i + s;
            int rc = min(row, NNODE);
            float dv = (row < NNODE) ? dinv[row]  : 0.f;
            float sb = (row < NNODE) ? sback[row] : 0.f;
            uint32 wy = btab[(size_t)rc * 32 + d2];
            float xl = __uint_as_float(wy << 16) * sb;          // x = y*sback (bf16 exact-scale)
            float xh = __uint_as_float(wy & 0xffff0000u) * sb;
            float sA = s ? aA1 : aA0, sB = s ? aB1 : aB0;
            float sC = s ? aC1 : aC0, sD = s ? aD1 : aD0;
            float p1l = fmaf(dv * invS, sA, xl);    // (L+I)@x
            float p1h = fmaf(dv * invS, sB, xh);
            float p2l = (dv * invS2) * sC;          // L@(x*x)
            float p2h = (dv * invS2) * sD;
            if (h == 0) {
                int rr = wid * 16 + i + s;
                int cbx = (4 * d2) ^ ((rr & 7) << 4);
                *(uint32*)&P1s[rr * 64 + (cbx >> 1)] = packbf(p1l, p1h);
                *(uint32*)&P2s[rr * 64 + (cbx >> 1)] = packbf(p2l, p2h);
            }
        }
    }
    __syncthreads();

    // ---- MFMA phase: wave wid computes cols [16*wid, 16*wid+16) for all 64 rows ----
    int l15 = lane & 15;
    int l4  = lane >> 4;
    int n0  = wid * 16;

    bf16x8 wf[2], wif[2];
    #pragma unroll
    for (int kt = 0; kt < 2; ++kt) {
        const float* wr  = W  + (size_t)(n0 + l15) * 64 + kt * 32 + l4 * 8;
        const float* wir = Wi + (size_t)(n0 + l15) * 64 + kt * 32 + l4 * 8;
        f32x4 a0 = *(const f32x4*)wr;
        f32x4 a1 = *(const f32x4*)(wr + 4);
        f32x4 c0 = *(const f32x4*)wir;
        f32x4 c1 = *(const f32x4*)(wir + 4);
        bf16x8 t0, t1;
        #pragma unroll
        for (int j = 0; j < 4; ++j) {
            t0[j]     = (short)f2bf(a0[j]);
            t0[j + 4] = (short)f2bf(a1[j]);
            t1[j]     = (short)f2bf(c0[j]);
            t1[j + 4] = (short)f2bf(c1[j]);
        }
        wf[kt]  = t0;
        wif[kt] = t1;
    }
    float bias_v = b[n0 + l15] + bi[n0 + l15];

    f32x4 acc0 = {0.f,0.f,0.f,0.f}, acc1v = {0.f,0.f,0.f,0.f};
    f32x4 acc2v = {0.f,0.f,0.f,0.f}, acc3 = {0.f,0.f,0.f,0.f};
    f32x4* accp[4] = {&acc0, &acc1v, &acc2v, &acc3};

    #pragma unroll
    for (int mt = 0; mt < 4; ++mt) {
        #pragma unroll
        for (int kt = 0; kt < 2; ++kt) {
            int rl = mt * 16 + l15;
            int cbx = (kt * 64 + l4 * 16) ^ ((rl & 7) << 4);
            int idx = rl * 64 + (cbx >> 1);
            bf16x8 a1f = *(const bf16x8*)&P1s[idx];
            bf16x8 a2f = *(const bf16x8*)&P2s[idx];
            *accp[mt] = __builtin_amdgcn_mfma_f32_16x16x32_bf16(a1f, wf[kt],  *accp[mt], 0, 0, 0);
            *accp[mt] = __builtin_amdgcn_mfma_f32_16x16x32_bf16(a2f, wif[kt], *accp[mt], 0, 0, 0);
        }
    }

    // C layout: col = lane&15, row = (lane>>4)*4 + j (+ mt*16). Write tables.
    #pragma unroll
    for (int mt = 0; mt < 4; ++mt) {
        #pragma unroll
        for (int j = 0; j < 4; ++j) {
            int r = base + mt * 16 + l4 * 4 + j;
            float o = fmaxf((*accp[mt])[j] + bias_v, 0.0f);
            float wsc = (r < NNODE) ? wout[r] : 0.0f;
            float oy = o * wsc;
            float oyn = __shfl_xor(oy, 1);
            if (((l15 & 1) == 0) && r < NNODE) {
                obtab[(size_t)r * 32 + ((n0 + l15) >> 1)] = packbf(oy, oyn);
                if (oftab)
                    oftab[(size_t)r * 32 + ((n0 + l15) >> 1)] =
                        (ushort)(f2fp8(FSCALE * oy) | (f2fp8(FSCALE * oyn) << 8));
            }
        }
    }
}

// ---------------- scoring + loss ----------------

__global__ __launch_bounds__(256) void score_kernel(
    const int* __restrict__ user, const int* __restrict__ item_i,
    const int* __restrict__ item_j,
    const float* __restrict__ eu, const float* __restrict__ ei,
    const uint32* __restrict__ g1tab, const uint32* __restrict__ g2tab,
    const float* __restrict__ sback,
    float* __restrict__ out, int B, int nwaves)
{
    int tid = threadIdx.x;
    int lane = tid & 63;
    int wv = tid >> 6;
    int gw = blockIdx.x * 4 + wv;
    int h = lane >> 5, d2 = lane & 31;

    float spacc = 0.0f;
    for (int w = gw; w < B; w += nwaves) {
        int u  = user[w];
        int i0 = item_i[w];
        int j0 = item_j[w];
        int ii = USER_NUM + i0;
        int jj = USER_NUM + j0;

        float e0u = eu[(size_t)u  * DDIM + lane];
        float e0i = ei[(size_t)i0 * DDIM + lane];
        float e0j = ei[(size_t)j0 * DDIM + lane];
        float di = e0u * e0i;
        float dj = e0u * e0j;

        const uint32* tb = h ? g2tab : g1tab;
        float su = sback[u], si2 = sback[ii], sj2 = sback[jj];
        uint32 wu = tb[(size_t)u  * 32 + d2];
        uint32 wi = tb[(size_t)ii * 32 + d2];
        uint32 wj = tb[(size_t)jj * 32 + d2];
        float u0 = __uint_as_float(wu << 16) * su,   u1 = __uint_as_float(wu & 0xffff0000u) * su;
        float i0f = __uint_as_float(wi << 16) * si2, i1f = __uint_as_float(wi & 0xffff0000u) * si2;
        float j0f = __uint_as_float(wj << 16) * sj2, j1f = __uint_as_float(wj & 0xffff0000u) * sj2;
        di += u0 * i0f + u1 * i1f;
        dj += u0 * j0f + u1 * j1f;

        for (int off = 32; off; off >>= 1) {
            di += __shfl_xor(di, off);
            dj += __shfl_xor(dj, off);
        }
        if (lane == 0) {
            out[w] = di;
            out[B + w] = dj;
            float x = di - dj;
            spacc += fmaxf(-x, 0.0f) + log1pf(expf(-fabsf(x)));   // softplus(-x)
        }
    }

    __shared__ float sred[4];
    if (lane == 0) sred[wv] = spacc;
    __syncthreads();
    if (tid == 0)
        atomicAdd(&out[2 * B], sred[0] + sred[1] + sred[2] + sred[3]);
}

// ---------------- launch ----------------

extern "C" void kernel_launch(void* const* d_in, const int* in_sizes, int n_in,
                              void* d_out, int out_size, void* d_ws, size_t ws_size,
                              hipStream_t stream) {
    const int*   user       = (const int*)d_in[0];
    const int*   item_i     = (const int*)d_in[1];
    const int*   item_j     = (const int*)d_in[2];
    const int*   rows       = (const int*)d_in[3];
    const int*   cols       = (const int*)d_in[4];
    const float* embed_user = (const float*)d_in[6];
    const float* embed_item = (const float*)d_in[7];
    const float* W1  = (const float*)d_in[8];
    const float* b1  = (const float*)d_in[9];
    const float* Wi1 = (const float*)d_in[10];
    const float* bi1 = (const float*)d_in[11];
    const float* W2  = (const float*)d_in[12];
    const float* b2  = (const float*)d_in[13];
    const float* Wi2 = (const float*)d_in[14];
    const float* bi2 = (const float*)d_in[15];

    int B = in_sizes[0];
    int E = in_sizes[3];
    float* out = (float*)d_out;

    char* ws = (char*)d_ws;
    size_t off = 0;
    auto alloc = [&](size_t bytes) -> void* {
        void* p = ws + off;
        off += (bytes + 255) & ~(size_t)255;
        return p;
    };
    uint32* b1tab    = (uint32*)alloc((size_t)(NNODE + 1) * 32 * 4);   // bf16 tables 18.5MB
    uint32* b2tab    = (uint32*)alloc((size_t)(NNODE + 1) * 32 * 4);
    uint32* b3tab    = (uint32*)alloc((size_t)(NNODE + 1) * 32 * 4);
    ushort* f1tab    = (ushort*)alloc((size_t)(NNODE + 1) * 32 * 2);   // fp8 tables 9.2MB
    ushort* f2tab    = (ushort*)alloc((size_t)(NNODE + 1) * 32 * 2);
    uint2*  edge2    = (uint2*)alloc((size_t)E * 8);                   // 16MB
    int*    row_ptr  = (int*)alloc((size_t)(NNODE + 1) * 4);
    int*    csr_col  = (int*)alloc((size_t)E * 4);
    uint32* staged   = (uint32*)alloc((size_t)E * 4);
    float*  dinv     = (float*)alloc((size_t)NNODE * 4);
    float*  wout     = (float*)alloc((size_t)NNODE * 4);
    float*  sback    = (float*)alloc((size_t)NNODE * 4);
    int*    totals   = (int*)alloc((size_t)NBUCK * 4);
    int*    bucket_off = (int*)alloc((size_t)(NBUCK + 1) * 4);
    int     nblocks  = (E + EPB - 1) / EPB;            // 245
    int*    blkcnt   = (int*)alloc((size_t)nblocks * NBUCK * 4);

    bucket_count_kernel<<<nblocks, 1024, 0, stream>>>(rows, blkcnt, E);
    bucket_block_scan_kernel<<<NBUCK, 256, 0, stream>>>(blkcnt, totals, nblocks);
    bucket_off_kernel<<<1, 1024, 0, stream>>>(totals, bucket_off, row_ptr, E);
    stage_kernel<<<nblocks, 1024, 0, stream>>>(rows, cols, blkcnt, bucket_off, staged, E);
    build_kernel<<<NBUCK, 256, 0, stream>>>(staged, bucket_off, row_ptr, csr_col,
                                            dinv, wout, sback);
    edge2_kernel<<<(E + 255) / 256, 256, 0, stream>>>(csr_col, sback, edge2, E);

    pack1_kernel<<<((NNODE + 1) * 32 + 255) / 256, 256, 0, stream>>>(
        embed_user, embed_item, wout, b1tab, b2tab, f1tab, f2tab);

    const int GNNB = (NNODE + 63) / 64;   // 2254
    gnn_layer_kernel<<<GNNB, 256, 0, stream>>>(
        f1tab, b1tab, edge2, row_ptr, sback, dinv, wout,
        W1, b1, Wi1, bi1, b2tab, f2tab);
    gnn_layer_kernel<<<GNNB, 256, 0, stream>>>(
        f2tab, b2tab, edge2, row_ptr, sback, dinv, wout,
        W2, b2, Wi2, bi2, b3tab, nullptr);

    init_loss_kernel<<<1, 64, 0, stream>>>(out, 2 * B);
    const int SCORE_BLOCKS = 256;                      // 1024 waves, 8 samples each
    score_kernel<<<SCORE_BLOCKS, 256, 0, stream>>>(
        user, item_i, item_j, embed_user, embed_item, b2tab, b3tab, sback,
        out, B, SCORE_BLOCKS * 4);
}

// Round 13
// 215.771 us; speedup vs baseline: 1.4770x; 1.4770x over previous
//
#include <hip/hip_runtime.h>
#include <hip/hip_bf16.h>
#include <cmath>

#define USER_NUM 52643
#define ITEM_NUM 91599
#define NNODE (USER_NUM + ITEM_NUM)   // 144242
#define DDIM 64
#define NBUCK 564                     // ceil(NNODE/256)
#define EPB 8192                      // edges per staging block
#define BCAP 8192                     // max edges per bucket
#define SY 512.0f                     // fp8 y scale
#define SZ 65536.0f                   // fp8 z scale

typedef unsigned int uint32;
typedef unsigned short ushort;

using bf16x8 = __attribute__((ext_vector_type(8))) short;
using f32x4  = __attribute__((ext_vector_type(4))) float;
using f32x2  = __attribute__((ext_vector_type(2))) float;

__device__ __forceinline__ uint32 f2bf(float f) {
    uint32 u = __float_as_uint(f);
    u += 0x7fffu + ((u >> 16) & 1u);   // round-to-nearest-even
    return u >> 16;
}
__device__ __forceinline__ uint32 packbf(float lo, float hi) {
    return (f2bf(hi) << 16) | f2bf(lo);
}

// HW decode: 2 fp8(e4m3fn) bytes (compile-time word sel) -> 2 f32
template <bool HI>
__device__ __forceinline__ f32x2 fp8x2_to_f32(uint32 u) {
    return __builtin_amdgcn_cvt_pk_f32_fp8((int)u, HI);
}

// HW encode: 2 f32 -> 2 fp8 bytes into lo/hi word of old (compile-time sel)
template <bool HI>
__device__ __forceinline__ uint32 fp8pack2(float a, float b, uint32 old) {
    return (uint32)__builtin_amdgcn_cvt_pk_fp8_f32(a, b, (int)old, HI);
}

// ---------------- small utility kernels ----------------

__global__ void init_loss_kernel(float* __restrict__ out, int loss_idx) {
    if (threadIdx.x == 0) out[loss_idx] = 0.0f;
}

// ---------------- bucketed CSR build (all global writes dense) ----------------

__global__ __launch_bounds__(1024) void bucket_count_kernel(
    const int* __restrict__ rows, int* __restrict__ blkcnt, int E)
{
    __shared__ int cnt[NBUCK];
    int t = threadIdx.x;
    for (int i = t; i < NBUCK; i += 1024) cnt[i] = 0;
    __syncthreads();
    int base = blockIdx.x * EPB;
    for (int i = t; i < EPB; i += 1024) {
        int e = base + i;
        if (e < E) atomicAdd(&cnt[rows[e] >> 8], 1);
    }
    __syncthreads();
    for (int i = t; i < NBUCK; i += 1024) blkcnt[blockIdx.x * NBUCK + i] = cnt[i];
}

__global__ __launch_bounds__(256) void bucket_block_scan_kernel(
    int* __restrict__ blkcnt, int* __restrict__ totals, int nblocks)
{
    __shared__ int wsum[4];
    int b = blockIdx.x, t = threadIdx.x;
    int lane = t & 63, wid = t >> 6;
    int c = (t < nblocks) ? blkcnt[t * NBUCK + b] : 0;
    int v = c;
    #pragma unroll
    for (int d = 1; d < 64; d <<= 1) {
        int src = (lane >= d) ? (lane - d) : lane;
        int tmp = __shfl(v, src);
        v += (lane >= d) ? tmp : 0;
    }
    if (lane == 63) wsum[wid] = v;
    __syncthreads();
    int woff = 0;
    for (int w = 0; w < wid; ++w) woff += wsum[w];
    int excl = woff + v - c;
    if (t < nblocks) blkcnt[t * NBUCK + b] = excl;
    if (t == 255) totals[b] = excl + c;
}

__global__ __launch_bounds__(1024) void bucket_off_kernel(
    const int* __restrict__ totals, int* __restrict__ bucket_off,
    int* __restrict__ row_ptr, int E)
{
    __shared__ int s[1024];
    int t = threadIdx.x;
    int v = (t < NBUCK) ? totals[t] : 0;
    s[t] = v;
    __syncthreads();
    #pragma unroll
    for (int d = 1; d < 1024; d <<= 1) {
        int add = (t >= d) ? s[t - d] : 0;
        __syncthreads();
        s[t] += add;
        __syncthreads();
    }
    if (t < NBUCK) bucket_off[t] = s[t] - v;
    if (t == 0) { bucket_off[NBUCK] = E; row_ptr[NNODE] = E; }
}

__global__ __launch_bounds__(1024) void stage_kernel(
    const int* __restrict__ rows, const int* __restrict__ cols,
    const int* __restrict__ blkcnt, const int* __restrict__ bucket_off,
    uint32* __restrict__ staged, int E)
{
    __shared__ int cnt[NBUCK];
    __shared__ int basel[NBUCK];
    int t = threadIdx.x;
    for (int i = t; i < NBUCK; i += 1024) {
        cnt[i] = 0;
        basel[i] = bucket_off[i] + blkcnt[blockIdx.x * NBUCK + i];
    }
    __syncthreads();
    int base = blockIdx.x * EPB;
    for (int i = t; i < EPB; i += 1024) {
        int e = base + i;
        if (e < E) {
            int r = rows[e];
            int bkt = r >> 8;
            int rank = atomicAdd(&cnt[bkt], 1);
            staged[basel[bkt] + rank] = ((uint32)(r & 255) << 18) | (uint32)cols[e];
        }
    }
}

// K6: degrees -> row_ptr/dinv/wout/sback; csr_col written PRE-SHIFTED (col<<5).
__global__ __launch_bounds__(256) void build_kernel(
    const uint32* __restrict__ staged, const int* __restrict__ bucket_off,
    int* __restrict__ row_ptr, int* __restrict__ csr_col,
    float* __restrict__ dinv, float* __restrict__ wout, float* __restrict__ sback)
{
    __shared__ int cnt[256];
    __shared__ int off[256];
    __shared__ int wsum[4];
    __shared__ int colbuf[BCAP];
    int b = blockIdx.x, t = threadIdx.x;
    int lane = t & 63, wid = t >> 6;
    int eoff = bucket_off[b];
    int ecnt = bucket_off[b + 1] - eoff;

    cnt[t] = 0;
    __syncthreads();
    for (int i = t; i < ecnt; i += 256) atomicAdd(&cnt[staged[eoff + i] >> 18], 1);
    __syncthreads();

    int c = cnt[t];
    int v = c;
    #pragma unroll
    for (int d = 1; d < 64; d <<= 1) {
        int src = (lane >= d) ? (lane - d) : lane;
        int tmp = __shfl(v, src);
        v += (lane >= d) ? tmp : 0;
    }
    if (lane == 63) wsum[wid] = v;
    __syncthreads();
    int woff = 0;
    for (int w = 0; w < wid; ++w) woff += wsum[w];
    int excl = woff + v - c;
    off[t] = excl;

    int node = b * 256 + t;
    if (node < NNODE) {
        row_ptr[node] = eoff + excl;
        float df = (float)c;
        float dv = (c > 0) ? (1.0f / sqrtf(df)) : 0.0f;
        dinv[node]  = dv;
        wout[node]  = (c > 0) ? dv : 1.0f;
        sback[node] = (c > 0) ? sqrtf(df) : 1.0f;
    }
    __syncthreads();
    cnt[t] = 0;
    __syncthreads();
    for (int i = t; i < ecnt; i += 256) {
        uint32 w = staged[eoff + i];
        int rl = w >> 18;
        int rank = atomicAdd(&cnt[rl], 1);
        colbuf[off[rl] + rank] = (int)(w & 0x3FFFFu);
    }
    __syncthreads();
    for (int i = t; i < ecnt; i += 256) csr_col[eoff + i] = colbuf[i] << 5;
}

// pack layer-1: bf16 y-pair table (identity/score) + fp8 y+z word table (gathers).
// Zero dummy row NNODE.
__global__ void pack1_kernel(const float* __restrict__ eu, const float* __restrict__ ei,
                             const float* __restrict__ wout,
                             uint32* __restrict__ b1tab, uint32* __restrict__ b2tab,
                             uint32* __restrict__ f1tab, uint32* __restrict__ f2tab) {
    int t = blockIdx.x * 256 + threadIdx.x;     // t = n*32 + d2
    int n = t >> 5, d2 = t & 31;
    if (n > NNODE) return;
    if (n == NNODE) { b1tab[t] = 0; b2tab[t] = 0; f1tab[t] = 0; f2tab[t] = 0; return; }
    const float* xp = (n < USER_NUM) ? (eu + ((size_t)n << 6))
                                     : (ei + (((size_t)n - USER_NUM) << 6));
    float2 x2 = *(const float2*)(xp + 2 * d2);
    float wv = wout[n];
    float y0 = wv * x2.x, y1 = wv * x2.y;
    float z0 = wv * x2.x * x2.x, z1 = wv * x2.y * x2.y;
    b1tab[t] = packbf(y0, y1);
    uint32 w = fp8pack2<false>(SY * y0, SY * y1, 0u);
    w = fp8pack2<true>(SZ * z0, SZ * z1, w);
    f1tab[t] = w;
    (void)d2;
}

// ---------------- fused GNN layer ----------------
// Gather: dual-row chains (R10); per 2 edges: 1 col shuffle + 1 v_add addr +
// 1x 4B fp8 gather (y-pair lo16, z-pair hi16) + 2 HW cvt + 4 adds. No sback dep.
// Identity from bf16 table. Epilogue: MFMA; writes bf16 (+ fp8 y+z if oftab).

__global__ __launch_bounds__(256, 8) void gnn_layer_kernel(
    const uint32* __restrict__ ftab, const uint32* __restrict__ btab,
    const int* __restrict__ row_ptr, const int* __restrict__ csr_col,
    const float* __restrict__ sback, const float* __restrict__ dinv,
    const float* __restrict__ wout,
    const float* __restrict__ W, const float* __restrict__ b,
    const float* __restrict__ Wi, const float* __restrict__ bi,
    uint32* __restrict__ obtab, uint32* __restrict__ oftab)
{
    __shared__ unsigned short P1s[64 * 64];   // [row][dim] bf16, byte-col ^ ((row&7)<<4)
    __shared__ unsigned short P2s[64 * 64];

    int tid = threadIdx.x;
    int lane = tid & 63;
    int wid = tid >> 6;
    int h = lane >> 5;        // edge parity
    int d2 = lane & 31;       // dim-pair index
    int base = blockIdx.x * 64;
    int wbase = base + wid * 16;

    int rp = 0;
    if (lane <= 16) rp = row_ptr[min(wbase + lane, NNODE)];

    const float invSY = 1.0f / SY;
    const float invSZ = 1.0f / SZ;
    const int DUMMY = NNODE << 5;

    // ---- gather phase: 16 rows per wave, interleaved pairs ----
    for (int i = 0; i < 16; i += 2) {
        int e0a = __shfl(rp, i);
        int e1a = __shfl(rp, i + 1);
        int e1b = __shfl(rp, i + 2);
        int e0b = e1a;

        float aA0 = 0.f, aB0 = 0.f, aC0 = 0.f, aD0 = 0.f;
        float aA1 = 0.f, aB1 = 0.f, aC1 = 0.f, aD1 = 0.f;

        int eba = e0a, ebb = e0b;
        while (eba < e1a || ebb < e1b) {
            int ca = DUMMY, cb = DUMMY;
            int ea = eba + lane, eb2 = ebb + lane;
            if (ea < e1a)  ca = csr_col[ea];     // coalesced 4B, pre-shifted col<<5
            if (eb2 < e1b) cb = csr_col[eb2];
            int nna = e1a - eba; nna = (nna < 0) ? 0 : ((nna > 64) ? 64 : nna);
            int nnb = e1b - ebb; nnb = (nnb < 0) ? 0 : ((nnb > 64) ? 64 : nnb);
            int nn = max(nna, nnb);
            for (int k = 0; k < nn; k += 8) {
                uint32 ga[4], gb[4];
                #pragma unroll
                for (int u = 0; u < 4; ++u) {
                    int idx = k + 2 * u + h;
                    int cca = __shfl(ca, idx);           // dummies -> zero row
                    int ccb = __shfl(cb, idx);
                    ga[u] = ftab[(uint32)(cca + d2)];    // 4B: y-pair | z-pair
                    gb[u] = ftab[(uint32)(ccb + d2)];
                }
                #pragma unroll
                for (int u = 0; u < 4; ++u) {
                    f32x2 ya = fp8x2_to_f32<false>(ga[u]);
                    f32x2 za = fp8x2_to_f32<true>(ga[u]);
                    aA0 += ya.x; aB0 += ya.y; aC0 += za.x; aD0 += za.y;
                    f32x2 yb = fp8x2_to_f32<false>(gb[u]);
                    f32x2 zb = fp8x2_to_f32<true>(gb[u]);
                    aA1 += yb.x; aB1 += yb.y; aC1 += zb.x; aD1 += zb.y;
                }
            }
            eba += 64; ebb += 64;
        }

        // combine edge parities
        aA0 += __shfl_xor(aA0, 32); aB0 += __shfl_xor(aB0, 32);
        aC0 += __shfl_xor(aC0, 32); aD0 += __shfl_xor(aD0, 32);
        aA1 += __shfl_xor(aA1, 32); aB1 += __shfl_xor(aB1, 32);
        aC1 += __shfl_xor(aC1, 32); aD1 += __shfl_xor(aD1, 32);

        #pragma unroll
        for (int s = 0; s < 2; ++s) {
            int row = wbase + i + s;
            int rc = min(row, NNODE);
            float dv = (row < NNODE) ? dinv[row]  : 0.f;
            float sb = (row < NNODE) ? sback[row] : 0.f;
            uint32 wy = btab[(uint32)(rc * 32 + d2)];
            float xl = __uint_as_float(wy << 16) * sb;          // x = y*sback (exact scale)
            float xh = __uint_as_float(wy & 0xffff0000u) * sb;
            float sA = s ? aA1 : aA0, sB = s ? aB1 : aB0;
            float sC = s ? aC1 : aC0, sD = s ? aD1 : aD0;
            float p1l = fmaf(dv * invSY, sA, xl);   // (L+I)@x
            float p1h = fmaf(dv * invSY, sB, xh);
            float p2l = (dv * invSZ) * sC;          // L@(x*x)
            float p2h = (dv * invSZ) * sD;
            if (h == 0) {
                int rr = wid * 16 + i + s;
                int cbx = (4 * d2) ^ ((rr & 7) << 4);
                *(uint32*)&P1s[rr * 64 + (cbx >> 1)] = packbf(p1l, p1h);
                *(uint32*)&P2s[rr * 64 + (cbx >> 1)] = packbf(p2l, p2h);
            }
        }
    }
    __syncthreads();

    // ---- MFMA phase: wave wid computes cols [16*wid, 16*wid+16) for all 64 rows ----
    int l15 = lane & 15;
    int l4  = lane >> 4;
    int n0  = wid * 16;

    bf16x8 wf[2], wif[2];
    #pragma unroll
    for (int kt = 0; kt < 2; ++kt) {
        const float* wr  = W  + (size_t)(n0 + l15) * 64 + kt * 32 + l4 * 8;
        const float* wir = Wi + (size_t)(n0 + l15) * 64 + kt * 32 + l4 * 8;
        f32x4 a0 = *(const f32x4*)wr;
        f32x4 a1 = *(const f32x4*)(wr + 4);
        f32x4 c0 = *(const f32x4*)wir;
        f32x4 c1 = *(const f32x4*)(wir + 4);
        bf16x8 t0, t1;
        #pragma unroll
        for (int j = 0; j < 4; ++j) {
            t0[j]     = (short)f2bf(a0[j]);
            t0[j + 4] = (short)f2bf(a1[j]);
            t1[j]     = (short)f2bf(c0[j]);
            t1[j + 4] = (short)f2bf(c1[j]);
        }
        wf[kt]  = t0;
        wif[kt] = t1;
    }
    float bias_v = b[n0 + l15] + bi[n0 + l15];

    f32x4 acc0 = {0.f,0.f,0.f,0.f}, acc1v = {0.f,0.f,0.f,0.f};
    f32x4 acc2v = {0.f,0.f,0.f,0.f}, acc3 = {0.f,0.f,0.f,0.f};
    f32x4* accp[4] = {&acc0, &acc1v, &acc2v, &acc3};

    #pragma unroll
    for (int mt = 0; mt < 4; ++mt) {
        #pragma unroll
        for (int kt = 0; kt < 2; ++kt) {
            int rl = mt * 16 + l15;
            int cbx = (kt * 64 + l4 * 16) ^ ((rl & 7) << 4);
            int idx = rl * 64 + (cbx >> 1);
            bf16x8 a1f = *(const bf16x8*)&P1s[idx];
            bf16x8 a2f = *(const bf16x8*)&P2s[idx];
            *accp[mt] = __builtin_amdgcn_mfma_f32_16x16x32_bf16(a1f, wf[kt],  *accp[mt], 0, 0, 0);
            *accp[mt] = __builtin_amdgcn_mfma_f32_16x16x32_bf16(a2f, wif[kt], *accp[mt], 0, 0, 0);
        }
    }

    // C layout: col = lane&15, row = (lane>>4)*4 + j (+ mt*16). Write tables.
    #pragma unroll
    for (int mt = 0; mt < 4; ++mt) {
        #pragma unroll
        for (int j = 0; j < 4; ++j) {
            int r = base + mt * 16 + l4 * 4 + j;
            float o = fmaxf((*accp[mt])[j] + bias_v, 0.0f);
            float wsc = (r < NNODE) ? wout[r] : 0.0f;
            float oy = o * wsc;          // wout*o
            float oz = oy * o;           // wout*o^2
            float oyn = __shfl_xor(oy, 1);
            float ozn = __shfl_xor(oz, 1);
            if (((l15 & 1) == 0) && r < NNODE) {
                size_t oidx = (size_t)r * 32 + ((n0 + l15) >> 1);
                obtab[oidx] = packbf(oy, oyn);
                if (oftab) {
                    uint32 w = fp8pack2<false>(SY * oy, SY * oyn, 0u);
                    w = fp8pack2<true>(SZ * oz, SZ * ozn, w);
                    oftab[oidx] = w;
                }
            }
        }
    }
}

// ---------------- scoring + loss ----------------

__global__ __launch_bounds__(256) void score_kernel(
    const int* __restrict__ user, const int* __restrict__ item_i,
    const int* __restrict__ item_j,
    const float* __restrict__ eu, const float* __restrict__ ei,
    const uint32* __restrict__ g1tab, const uint32* __restrict__ g2tab,
    const float* __restrict__ sback,
    float* __restrict__ out, int B, int nwaves)
{
    int tid = threadIdx.x;
    int lane = tid & 63;
    int wv = tid >> 6;
    int gw = blockIdx.x * 4 + wv;
    int h = lane >> 5, d2 = lane & 31;

    float spacc = 0.0f;
    for (int w = gw; w < B; w += nwaves) {
        int u  = user[w];
        int i0 = item_i[w];
        int j0 = item_j[w];
        int ii = USER_NUM + i0;
        int jj = USER_NUM + j0;

        float e0u = eu[(size_t)u  * DDIM + lane];
        float e0i = ei[(size_t)i0 * DDIM + lane];
        float e0j = ei[(size_t)j0 * DDIM + lane];
        float di = e0u * e0i;
        float dj = e0u * e0j;

        const uint32* tb = h ? g2tab : g1tab;
        float su = sback[u], si2 = sback[ii], sj2 = sback[jj];
        uint32 wu = tb[(size_t)u  * 32 + d2];
        uint32 wi = tb[(size_t)ii * 32 + d2];
        uint32 wj = tb[(size_t)jj * 32 + d2];
        float u0 = __uint_as_float(wu << 16) * su,   u1 = __uint_as_float(wu & 0xffff0000u) * su;
        float i0f = __uint_as_float(wi << 16) * si2, i1f = __uint_as_float(wi & 0xffff0000u) * si2;
        float j0f = __uint_as_float(wj << 16) * sj2, j1f = __uint_as_float(wj & 0xffff0000u) * sj2;
        di += u0 * i0f + u1 * i1f;
        dj += u0 * j0f + u1 * j1f;

        for (int off = 32; off; off >>= 1) {
            di += __shfl_xor(di, off);
            dj += __shfl_xor(dj, off);
        }
        if (lane == 0) {
            out[w] = di;
            out[B + w] = dj;
            float x = di - dj;
            spacc += fmaxf(-x, 0.0f) + log1pf(expf(-fabsf(x)));   // softplus(-x)
        }
    }

    __shared__ float sred[4];
    if (lane == 0) sred[wv] = spacc;
    __syncthreads();
    if (tid == 0)
        atomicAdd(&out[2 * B], sred[0] + sred[1] + sred[2] + sred[3]);
}

// ---------------- launch ----------------

extern "C" void kernel_launch(void* const* d_in, const int* in_sizes, int n_in,
                              void* d_out, int out_size, void* d_ws, size_t ws_size,
                              hipStream_t stream) {
    const int*   user       = (const int*)d_in[0];
    const int*   item_i     = (const int*)d_in[1];
    const int*   item_j     = (const int*)d_in[2];
    const int*   rows       = (const int*)d_in[3];
    const int*   cols       = (const int*)d_in[4];
    const float* embed_user = (const float*)d_in[6];
    const float* embed_item = (const float*)d_in[7];
    const float* W1  = (const float*)d_in[8];
    const float* b1  = (const float*)d_in[9];
    const float* Wi1 = (const float*)d_in[10];
    const float* bi1 = (const float*)d_in[11];
    const float* W2  = (const float*)d_in[12];
    const float* b2  = (const float*)d_in[13];
    const float* Wi2 = (const float*)d_in[14];
    const float* bi2 = (const float*)d_in[15];

    int B = in_sizes[0];
    int E = in_sizes[3];
    float* out = (float*)d_out;

    char* ws = (char*)d_ws;
    size_t off = 0;
    auto alloc = [&](size_t bytes) -> void* {
        void* p = ws + off;
        off += (bytes + 255) & ~(size_t)255;
        return p;
    };
    uint32* b1tab    = (uint32*)alloc((size_t)(NNODE + 1) * 32 * 4);   // bf16 y tables
    uint32* b2tab    = (uint32*)alloc((size_t)(NNODE + 1) * 32 * 4);
    uint32* b3tab    = (uint32*)alloc((size_t)(NNODE + 1) * 32 * 4);
    uint32* f1tab    = (uint32*)alloc((size_t)(NNODE + 1) * 32 * 4);   // fp8 y+z tables
    uint32* f2tab    = (uint32*)alloc((size_t)(NNODE + 1) * 32 * 4);
    int*    row_ptr  = (int*)alloc((size_t)(NNODE + 1) * 4);
    int*    csr_col  = (int*)alloc((size_t)E * 4);
    uint32* staged   = (uint32*)alloc((size_t)E * 4);
    float*  dinv     = (float*)alloc((size_t)NNODE * 4);
    float*  wout     = (float*)alloc((size_t)NNODE * 4);
    float*  sback    = (float*)alloc((size_t)NNODE * 4);
    int*    totals   = (int*)alloc((size_t)NBUCK * 4);
    int*    bucket_off = (int*)alloc((size_t)(NBUCK + 1) * 4);
    int     nblocks  = (E + EPB - 1) / EPB;            // 245
    int*    blkcnt   = (int*)alloc((size_t)nblocks * NBUCK * 4);

    bucket_count_kernel<<<nblocks, 1024, 0, stream>>>(rows, blkcnt, E);
    bucket_block_scan_kernel<<<NBUCK, 256, 0, stream>>>(blkcnt, totals, nblocks);
    bucket_off_kernel<<<1, 1024, 0, stream>>>(totals, bucket_off, row_ptr, E);
    stage_kernel<<<nblocks, 1024, 0, stream>>>(rows, cols, blkcnt, bucket_off, staged, E);
    build_kernel<<<NBUCK, 256, 0, stream>>>(staged, bucket_off, row_ptr, csr_col,
                                            dinv, wout, sback);

    pack1_kernel<<<((NNODE + 1) * 32 + 255) / 256, 256, 0, stream>>>(
        embed_user, embed_item, wout, b1tab, b2tab, f1tab, f2tab);

    const int GNNB = (NNODE + 63) / 64;   // 2254
    gnn_layer_kernel<<<GNNB, 256, 0, stream>>>(
        f1tab, b1tab, row_ptr, csr_col, sback, dinv, wout,
        W1, b1, Wi1, bi1, b2tab, f2tab);
    gnn_layer_kernel<<<GNNB, 256, 0, stream>>>(
        f2tab, b2tab, row_ptr, csr_col, sback, dinv, wout,
        W2, b2, Wi2, bi2, b3tab, nullptr);

    init_loss_kernel<<<1, 64, 0, stream>>>(out, 2 * B);
    const int SCORE_BLOCKS = 256;                      // 1024 waves, 8 samples each
    score_kernel<<<SCORE_BLOCKS, 256, 0, stream>>>(
        user, item_i, item_j, embed_user, embed_item, b2tab, b3tab, sback,
        out, B, SCORE_BLOCKS * 4);
}

// Round 14
// 181.260 us; speedup vs baseline: 1.7582x; 1.1904x over previous
//
#include <hip/hip_runtime.h>
#include <hip/hip_bf16.h>
#include <cmath>

#define USER_NUM 52643
#define ITEM_NUM 91599
#define NNODE (USER_NUM + ITEM_NUM)   // 144242
#define DDIM 64
#define NBUCK 564                     // ceil(NNODE/256)
#define EPB 8192                      // edges per staging block
#define BCAP 8192                     // max edges per bucket
#define SY 512.0f                     // fp8 y scale
#define SZ 65536.0f                   // fp8 z scale

typedef unsigned int uint32;
typedef unsigned short ushort;

using bf16x8 = __attribute__((ext_vector_type(8))) short;
using f32x4  = __attribute__((ext_vector_type(4))) float;
using f32x2  = __attribute__((ext_vector_type(2))) float;

__device__ __forceinline__ uint32 f2bf(float f) {
    uint32 u = __float_as_uint(f);
    u += 0x7fffu + ((u >> 16) & 1u);   // round-to-nearest-even
    return u >> 16;
}
__device__ __forceinline__ uint32 packbf(float lo, float hi) {
    return (f2bf(hi) << 16) | f2bf(lo);
}

// HW decode: 2 fp8(e4m3fn) bytes (compile-time word sel) -> 2 f32
template <bool HI>
__device__ __forceinline__ f32x2 fp8x2_to_f32(uint32 u) {
    return __builtin_amdgcn_cvt_pk_f32_fp8((int)u, HI);
}

// HW encode: 2 f32 -> 2 fp8 bytes into lo/hi word of old (compile-time sel)
template <bool HI>
__device__ __forceinline__ uint32 fp8pack2(float a, float b, uint32 old) {
    return (uint32)__builtin_amdgcn_cvt_pk_fp8_f32(a, b, (int)old, HI);
}

// ---------------- small utility kernels ----------------

__global__ void init_loss_kernel(float* __restrict__ out, int loss_idx) {
    if (threadIdx.x == 0) out[loss_idx] = 0.0f;
}

// target row list for layer 2: only sampled nodes' g2 is ever read
__global__ void tgt_kernel(const int* __restrict__ user, const int* __restrict__ item_i,
                           const int* __restrict__ item_j, int* __restrict__ tgt, int B) {
    int w = blockIdx.x * 256 + threadIdx.x;
    if (w < B) {
        tgt[w]         = user[w];
        tgt[B + w]     = USER_NUM + item_i[w];
        tgt[2 * B + w] = USER_NUM + item_j[w];
    }
}

// ---------------- bucketed CSR build (all global writes dense) ----------------

__global__ __launch_bounds__(1024) void bucket_count_kernel(
    const int* __restrict__ rows, int* __restrict__ blkcnt, int E)
{
    __shared__ int cnt[NBUCK];
    int t = threadIdx.x;
    for (int i = t; i < NBUCK; i += 1024) cnt[i] = 0;
    __syncthreads();
    int base = blockIdx.x * EPB;
    for (int i = t; i < EPB; i += 1024) {
        int e = base + i;
        if (e < E) atomicAdd(&cnt[rows[e] >> 8], 1);
    }
    __syncthreads();
    for (int i = t; i < NBUCK; i += 1024) blkcnt[blockIdx.x * NBUCK + i] = cnt[i];
}

__global__ __launch_bounds__(256) void bucket_block_scan_kernel(
    int* __restrict__ blkcnt, int* __restrict__ totals, int nblocks)
{
    __shared__ int wsum[4];
    int b = blockIdx.x, t = threadIdx.x;
    int lane = t & 63, wid = t >> 6;
    int c = (t < nblocks) ? blkcnt[t * NBUCK + b] : 0;
    int v = c;
    #pragma unroll
    for (int d = 1; d < 64; d <<= 1) {
        int src = (lane >= d) ? (lane - d) : lane;
        int tmp = __shfl(v, src);
        v += (lane >= d) ? tmp : 0;
    }
    if (lane == 63) wsum[wid] = v;
    __syncthreads();
    int woff = 0;
    for (int w = 0; w < wid; ++w) woff += wsum[w];
    int excl = woff + v - c;
    if (t < nblocks) blkcnt[t * NBUCK + b] = excl;
    if (t == 255) totals[b] = excl + c;
}

__global__ __launch_bounds__(1024) void bucket_off_kernel(
    const int* __restrict__ totals, int* __restrict__ bucket_off,
    int* __restrict__ row_ptr, int E)
{
    __shared__ int s[1024];
    int t = threadIdx.x;
    int v = (t < NBUCK) ? totals[t] : 0;
    s[t] = v;
    __syncthreads();
    #pragma unroll
    for (int d = 1; d < 1024; d <<= 1) {
        int add = (t >= d) ? s[t - d] : 0;
        __syncthreads();
        s[t] += add;
        __syncthreads();
    }
    if (t < NBUCK) bucket_off[t] = s[t] - v;
    if (t == 0) { bucket_off[NBUCK] = E; row_ptr[NNODE] = E; }
}

__global__ __launch_bounds__(1024) void stage_kernel(
    const int* __restrict__ rows, const int* __restrict__ cols,
    const int* __restrict__ blkcnt, const int* __restrict__ bucket_off,
    uint32* __restrict__ staged, int E)
{
    __shared__ int cnt[NBUCK];
    __shared__ int basel[NBUCK];
    int t = threadIdx.x;
    for (int i = t; i < NBUCK; i += 1024) {
        cnt[i] = 0;
        basel[i] = bucket_off[i] + blkcnt[blockIdx.x * NBUCK + i];
    }
    __syncthreads();
    int base = blockIdx.x * EPB;
    for (int i = t; i < EPB; i += 1024) {
        int e = base + i;
        if (e < E) {
            int r = rows[e];
            int bkt = r >> 8;
            int rank = atomicAdd(&cnt[bkt], 1);
            staged[basel[bkt] + rank] = ((uint32)(r & 255) << 18) | (uint32)cols[e];
        }
    }
}

// K6: degrees -> row_ptr/dinv/wout/sback; csr_col written PRE-SHIFTED (col<<5).
__global__ __launch_bounds__(256) void build_kernel(
    const uint32* __restrict__ staged, const int* __restrict__ bucket_off,
    int* __restrict__ row_ptr, int* __restrict__ csr_col,
    float* __restrict__ dinv, float* __restrict__ wout, float* __restrict__ sback)
{
    __shared__ int cnt[256];
    __shared__ int off[256];
    __shared__ int wsum[4];
    __shared__ int colbuf[BCAP];
    int b = blockIdx.x, t = threadIdx.x;
    int lane = t & 63, wid = t >> 6;
    int eoff = bucket_off[b];
    int ecnt = bucket_off[b + 1] - eoff;

    cnt[t] = 0;
    __syncthreads();
    for (int i = t; i < ecnt; i += 256) atomicAdd(&cnt[staged[eoff + i] >> 18], 1);
    __syncthreads();

    int c = cnt[t];
    int v = c;
    #pragma unroll
    for (int d = 1; d < 64; d <<= 1) {
        int src = (lane >= d) ? (lane - d) : lane;
        int tmp = __shfl(v, src);
        v += (lane >= d) ? tmp : 0;
    }
    if (lane == 63) wsum[wid] = v;
    __syncthreads();
    int woff = 0;
    for (int w = 0; w < wid; ++w) woff += wsum[w];
    int excl = woff + v - c;
    off[t] = excl;

    int node = b * 256 + t;
    if (node < NNODE) {
        row_ptr[node] = eoff + excl;
        float df = (float)c;
        float dv = (c > 0) ? (1.0f / sqrtf(df)) : 0.0f;
        dinv[node]  = dv;
        wout[node]  = (c > 0) ? dv : 1.0f;
        sback[node] = (c > 0) ? sqrtf(df) : 1.0f;
    }
    __syncthreads();
    cnt[t] = 0;
    __syncthreads();
    for (int i = t; i < ecnt; i += 256) {
        uint32 w = staged[eoff + i];
        int rl = w >> 18;
        int rank = atomicAdd(&cnt[rl], 1);
        colbuf[off[rl] + rank] = (int)(w & 0x3FFFFu);
    }
    __syncthreads();
    for (int i = t; i < ecnt; i += 256) csr_col[eoff + i] = colbuf[i] << 5;
}

// pack layer-1: bf16 y-pair table (identity/score) + fp8 y+z word table (gathers).
// Zero dummy row NNODE.
__global__ void pack1_kernel(const float* __restrict__ eu, const float* __restrict__ ei,
                             const float* __restrict__ wout,
                             uint32* __restrict__ b1tab, uint32* __restrict__ b2tab,
                             uint32* __restrict__ f1tab, uint32* __restrict__ f2tab) {
    int t = blockIdx.x * 256 + threadIdx.x;     // t = n*32 + d2
    int n = t >> 5, d2 = t & 31;
    if (n > NNODE) return;
    if (n == NNODE) { b1tab[t] = 0; b2tab[t] = 0; f1tab[t] = 0; f2tab[t] = 0; return; }
    const float* xp = (n < USER_NUM) ? (eu + ((size_t)n << 6))
                                     : (ei + (((size_t)n - USER_NUM) << 6));
    float2 x2 = *(const float2*)(xp + 2 * d2);
    float wv = wout[n];
    float y0 = wv * x2.x, y1 = wv * x2.y;
    float z0 = wv * x2.x * x2.x, z1 = wv * x2.y * x2.y;
    b1tab[t] = packbf(y0, y1);
    uint32 w = fp8pack2<false>(SY * y0, SY * y1, 0u);
    w = fp8pack2<true>(SZ * z0, SZ * z1, w);
    f1tab[t] = w;
    (void)d2;
}

// ---------------- fused GNN layer ----------------
// TGT=false: all NNODE rows (tiles of 64 consecutive rows).
// TGT=true : rows from tgt[] list (layer 2 only needs sampled rows: 15.7% of edges).
// Gather: dual-row chains; per 2 edges: 1 col shuffle + addr add + 1x 4B fp8 gather
// (y-pair lo16, z-pair hi16) + 2 HW cvt + 4 adds. Epilogue: MFMA; bf16 (+fp8) tables.

template <bool TGT>
__global__ __launch_bounds__(256, 8) void gnn_layer_kernel(
    const uint32* __restrict__ ftab, const uint32* __restrict__ btab,
    const int* __restrict__ row_ptr, const int* __restrict__ csr_col,
    const int* __restrict__ tgt,
    const float* __restrict__ sback, const float* __restrict__ dinv,
    const float* __restrict__ wout,
    const float* __restrict__ W, const float* __restrict__ b,
    const float* __restrict__ Wi, const float* __restrict__ bi,
    uint32* __restrict__ obtab, uint32* __restrict__ oftab)
{
    __shared__ unsigned short P1s[64 * 64];   // [row][dim] bf16, byte-col ^ ((row&7)<<4)
    __shared__ unsigned short P2s[64 * 64];

    int tid = threadIdx.x;
    int lane = tid & 63;
    int wid = tid >> 6;
    int h = lane >> 5;        // edge parity
    int d2 = lane & 31;       // dim-pair index
    int base = blockIdx.x * 64;
    int wbase = base + wid * 16;

    int rpS = 0, rpE = 0, trv = 0;
    if (TGT) {
        if (lane < 16) {
            trv = tgt[wbase + lane];        // TGT grid is exact: no bounds check
            rpS = row_ptr[trv];
            rpE = row_ptr[trv + 1];
        }
    } else {
        if (lane <= 16) rpS = row_ptr[min(wbase + lane, NNODE)];
    }

    const float invSY = 1.0f / SY;
    const float invSZ = 1.0f / SZ;
    const int DUMMY = NNODE << 5;

    // ---- gather phase: 16 rows per wave, interleaved pairs ----
    for (int i = 0; i < 16; i += 2) {
        int e0a, e1a, e0b, e1b;
        if (TGT) {
            e0a = __shfl(rpS, i);     e1a = __shfl(rpE, i);
            e0b = __shfl(rpS, i + 1); e1b = __shfl(rpE, i + 1);
        } else {
            e0a = __shfl(rpS, i);
            e1a = __shfl(rpS, i + 1);
            e1b = __shfl(rpS, i + 2);
            e0b = e1a;
        }

        float aA0 = 0.f, aB0 = 0.f, aC0 = 0.f, aD0 = 0.f;
        float aA1 = 0.f, aB1 = 0.f, aC1 = 0.f, aD1 = 0.f;

        int eba = e0a, ebb = e0b;
        while (eba < e1a || ebb < e1b) {
            int ca = DUMMY, cb = DUMMY;
            int ea = eba + lane, eb2 = ebb + lane;
            if (ea < e1a)  ca = csr_col[ea];     // coalesced 4B, pre-shifted col<<5
            if (eb2 < e1b) cb = csr_col[eb2];
            int nna = e1a - eba; nna = (nna < 0) ? 0 : ((nna > 64) ? 64 : nna);
            int nnb = e1b - ebb; nnb = (nnb < 0) ? 0 : ((nnb > 64) ? 64 : nnb);
            int nn = max(nna, nnb);
            for (int k = 0; k < nn; k += 8) {
                uint32 ga[4], gb[4];
                #pragma unroll
                for (int u = 0; u < 4; ++u) {
                    int idx = k + 2 * u + h;
                    int cca = __shfl(ca, idx);           // dummies -> zero row
                    int ccb = __shfl(cb, idx);
                    ga[u] = ftab[(uint32)(cca + d2)];    // 4B: y-pair | z-pair
                    gb[u] = ftab[(uint32)(ccb + d2)];
                }
                #pragma unroll
                for (int u = 0; u < 4; ++u) {
                    f32x2 ya = fp8x2_to_f32<false>(ga[u]);
                    f32x2 za = fp8x2_to_f32<true>(ga[u]);
                    aA0 += ya.x; aB0 += ya.y; aC0 += za.x; aD0 += za.y;
                    f32x2 yb = fp8x2_to_f32<false>(gb[u]);
                    f32x2 zb = fp8x2_to_f32<true>(gb[u]);
                    aA1 += yb.x; aB1 += yb.y; aC1 += zb.x; aD1 += zb.y;
                }
            }
            eba += 64; ebb += 64;
        }

        // combine edge parities
        aA0 += __shfl_xor(aA0, 32); aB0 += __shfl_xor(aB0, 32);
        aC0 += __shfl_xor(aC0, 32); aD0 += __shfl_xor(aD0, 32);
        aA1 += __shfl_xor(aA1, 32); aB1 += __shfl_xor(aB1, 32);
        aC1 += __shfl_xor(aC1, 32); aD1 += __shfl_xor(aD1, 32);

        #pragma unroll
        for (int s = 0; s < 2; ++s) {
            int row, rc;
            if (TGT) { row = __shfl(trv, i + s); rc = row; }
            else     { row = wbase + i + s;      rc = min(row, NNODE); }
            bool valid = TGT || (row < NNODE);
            float dv = valid ? dinv[rc]  : 0.f;
            float sb = valid ? sback[rc] : 0.f;
            uint32 wy = btab[(uint32)(rc * 32 + d2)];
            float xl = __uint_as_float(wy << 16) * sb;          // x = y*sback (exact scale)
            float xh = __uint_as_float(wy & 0xffff0000u) * sb;
            float sA = s ? aA1 : aA0, sB = s ? aB1 : aB0;
            float sC = s ? aC1 : aC0, sD = s ? aD1 : aD0;
            float p1l = fmaf(dv * invSY, sA, xl);   // (L+I)@x
            float p1h = fmaf(dv * invSY, sB, xh);
            float p2l = (dv * invSZ) * sC;          // L@(x*x)
            float p2h = (dv * invSZ) * sD;
            if (h == 0) {
                int rr = wid * 16 + i + s;
                int cbx = (4 * d2) ^ ((rr & 7) << 4);
                *(uint32*)&P1s[rr * 64 + (cbx >> 1)] = packbf(p1l, p1h);
                *(uint32*)&P2s[rr * 64 + (cbx >> 1)] = packbf(p2l, p2h);
            }
        }
    }
    __syncthreads();

    // ---- MFMA phase: wave wid computes cols [16*wid, 16*wid+16) for all 64 rows ----
    int l15 = lane & 15;
    int l4  = lane >> 4;
    int n0  = wid * 16;

    bf16x8 wf[2], wif[2];
    #pragma unroll
    for (int kt = 0; kt < 2; ++kt) {
        const float* wr  = W  + (size_t)(n0 + l15) * 64 + kt * 32 + l4 * 8;
        const float* wir = Wi + (size_t)(n0 + l15) * 64 + kt * 32 + l4 * 8;
        f32x4 a0 = *(const f32x4*)wr;
        f32x4 a1 = *(const f32x4*)(wr + 4);
        f32x4 c0 = *(const f32x4*)wir;
        f32x4 c1 = *(const f32x4*)(wir + 4);
        bf16x8 t0, t1;
        #pragma unroll
        for (int j = 0; j < 4; ++j) {
            t0[j]     = (short)f2bf(a0[j]);
            t0[j + 4] = (short)f2bf(a1[j]);
            t1[j]     = (short)f2bf(c0[j]);
            t1[j + 4] = (short)f2bf(c1[j]);
        }
        wf[kt]  = t0;
        wif[kt] = t1;
    }
    float bias_v = b[n0 + l15] + bi[n0 + l15];

    f32x4 acc0 = {0.f,0.f,0.f,0.f}, acc1v = {0.f,0.f,0.f,0.f};
    f32x4 acc2v = {0.f,0.f,0.f,0.f}, acc3 = {0.f,0.f,0.f,0.f};
    f32x4* accp[4] = {&acc0, &acc1v, &acc2v, &acc3};

    #pragma unroll
    for (int mt = 0; mt < 4; ++mt) {
        #pragma unroll
        for (int kt = 0; kt < 2; ++kt) {
            int rl = mt * 16 + l15;
            int cbx = (kt * 64 + l4 * 16) ^ ((rl & 7) << 4);
            int idx = rl * 64 + (cbx >> 1);
            bf16x8 a1f = *(const bf16x8*)&P1s[idx];
            bf16x8 a2f = *(const bf16x8*)&P2s[idx];
            *accp[mt] = __builtin_amdgcn_mfma_f32_16x16x32_bf16(a1f, wf[kt],  *accp[mt], 0, 0, 0);
            *accp[mt] = __builtin_amdgcn_mfma_f32_16x16x32_bf16(a2f, wif[kt], *accp[mt], 0, 0, 0);
        }
    }

    // C layout: col = lane&15, row = (lane>>4)*4 + j (+ mt*16). Write tables.
    #pragma unroll
    for (int mt = 0; mt < 4; ++mt) {
        #pragma unroll
        for (int j = 0; j < 4; ++j) {
            int ridx = base + mt * 16 + l4 * 4 + j;
            int r = TGT ? tgt[ridx] : ridx;
            bool valid = TGT || (r < NNODE);
            float o = fmaxf((*accp[mt])[j] + bias_v, 0.0f);
            float wsc = valid ? wout[r] : 0.0f;
            float oy = o * wsc;          // wout*o
            float oz = oy * o;           // wout*o^2
            float oyn = __shfl_xor(oy, 1);
            float ozn = __shfl_xor(oz, 1);
            if (((l15 & 1) == 0) && valid) {
                size_t oidx = (size_t)r * 32 + ((n0 + l15) >> 1);
                obtab[oidx] = packbf(oy, oyn);
                if (oftab) {
                    uint32 w = fp8pack2<false>(SY * oy, SY * oyn, 0u);
                    w = fp8pack2<true>(SZ * oz, SZ * ozn, w);
                    oftab[oidx] = w;
                }
            }
        }
    }
}

// ---------------- scoring + loss ----------------

__global__ __launch_bounds__(256) void score_kernel(
    const int* __restrict__ user, const int* __restrict__ item_i,
    const int* __restrict__ item_j,
    const float* __restrict__ eu, const float* __restrict__ ei,
    const uint32* __restrict__ g1tab, const uint32* __restrict__ g2tab,
    const float* __restrict__ sback,
    float* __restrict__ out, int B, int nwaves)
{
    int tid = threadIdx.x;
    int lane = tid & 63;
    int wv = tid >> 6;
    int gw = blockIdx.x * 4 + wv;
    int h = lane >> 5, d2 = lane & 31;

    float spacc = 0.0f;
    for (int w = gw; w < B; w += nwaves) {
        int u  = user[w];
        int i0 = item_i[w];
        int j0 = item_j[w];
        int ii = USER_NUM + i0;
        int jj = USER_NUM + j0;

        float e0u = eu[(size_t)u  * DDIM + lane];
        float e0i = ei[(size_t)i0 * DDIM + lane];
        float e0j = ei[(size_t)j0 * DDIM + lane];
        float di = e0u * e0i;
        float dj = e0u * e0j;

        const uint32* tb = h ? g2tab : g1tab;
        float su = sback[u], si2 = sback[ii], sj2 = sback[jj];
        uint32 wu = tb[(size_t)u  * 32 + d2];
        uint32 wi = tb[(size_t)ii * 32 + d2];
        uint32 wj = tb[(size_t)jj * 32 + d2];
        float u0 = __uint_as_float(wu << 16) * su,   u1 = __uint_as_float(wu & 0xffff0000u) * su;
        float i0f = __uint_as_float(wi << 16) * si2, i1f = __uint_as_float(wi & 0xffff0000u) * si2;
        float j0f = __uint_as_float(wj << 16) * sj2, j1f = __uint_as_float(wj & 0xffff0000u) * sj2;
        di += u0 * i0f + u1 * i1f;
        dj += u0 * j0f + u1 * j1f;

        for (int off = 32; off; off >>= 1) {
            di += __shfl_xor(di, off);
            dj += __shfl_xor(dj, off);
        }
        if (lane == 0) {
            out[w] = di;
            out[B + w] = dj;
            float x = di - dj;
            spacc += fmaxf(-x, 0.0f) + log1pf(expf(-fabsf(x)));   // softplus(-x)
        }
    }

    __shared__ float sred[4];
    if (lane == 0) sred[wv] = spacc;
    __syncthreads();
    if (tid == 0)
        atomicAdd(&out[2 * B], sred[0] + sred[1] + sred[2] + sred[3]);
}

// ---------------- launch ----------------

extern "C" void kernel_launch(void* const* d_in, const int* in_sizes, int n_in,
                              void* d_out, int out_size, void* d_ws, size_t ws_size,
                              hipStream_t stream) {
    const int*   user       = (const int*)d_in[0];
    const int*   item_i     = (const int*)d_in[1];
    const int*   item_j     = (const int*)d_in[2];
    const int*   rows       = (const int*)d_in[3];
    const int*   cols       = (const int*)d_in[4];
    const float* embed_user = (const float*)d_in[6];
    const float* embed_item = (const float*)d_in[7];
    const float* W1  = (const float*)d_in[8];
    const float* b1  = (const float*)d_in[9];
    const float* Wi1 = (const float*)d_in[10];
    const float* bi1 = (const float*)d_in[11];
    const float* W2  = (const float*)d_in[12];
    const float* b2  = (const float*)d_in[13];
    const float* Wi2 = (const float*)d_in[14];
    const float* bi2 = (const float*)d_in[15];

    int B = in_sizes[0];
    int E = in_sizes[3];
    float* out = (float*)d_out;

    char* ws = (char*)d_ws;
    size_t off = 0;
    auto alloc = [&](size_t bytes) -> void* {
        void* p = ws + off;
        off += (bytes + 255) & ~(size_t)255;
        return p;
    };
    uint32* b1tab    = (uint32*)alloc((size_t)(NNODE + 1) * 32 * 4);   // bf16 y tables
    uint32* b2tab    = (uint32*)alloc((size_t)(NNODE + 1) * 32 * 4);
    uint32* b3tab    = (uint32*)alloc((size_t)(NNODE + 1) * 32 * 4);
    uint32* f1tab    = (uint32*)alloc((size_t)(NNODE + 1) * 32 * 4);   // fp8 y+z tables
    uint32* f2tab    = (uint32*)alloc((size_t)(NNODE + 1) * 32 * 4);
    int*    row_ptr  = (int*)alloc((size_t)(NNODE + 1) * 4);
    int*    csr_col  = (int*)alloc((size_t)E * 4);
    uint32* staged   = (uint32*)alloc((size_t)E * 4);
    float*  dinv     = (float*)alloc((size_t)NNODE * 4);
    float*  wout     = (float*)alloc((size_t)NNODE * 4);
    float*  sback    = (float*)alloc((size_t)NNODE * 4);
    int*    totals   = (int*)alloc((size_t)NBUCK * 4);
    int*    bucket_off = (int*)alloc((size_t)(NBUCK + 1) * 4);
    int*    tgt      = (int*)alloc((size_t)(3 * B) * 4);
    int     nblocks  = (E + EPB - 1) / EPB;            // 245
    int*    blkcnt   = (int*)alloc((size_t)nblocks * NBUCK * 4);

    bucket_count_kernel<<<nblocks, 1024, 0, stream>>>(rows, blkcnt, E);
    bucket_block_scan_kernel<<<NBUCK, 256, 0, stream>>>(blkcnt, totals, nblocks);
    bucket_off_kernel<<<1, 1024, 0, stream>>>(totals, bucket_off, row_ptr, E);
    stage_kernel<<<nblocks, 1024, 0, stream>>>(rows, cols, blkcnt, bucket_off, staged, E);
    build_kernel<<<NBUCK, 256, 0, stream>>>(staged, bucket_off, row_ptr, csr_col,
                                            dinv, wout, sback);
    tgt_kernel<<<(B + 255) / 256, 256, 0, stream>>>(user, item_i, item_j, tgt, B);

    pack1_kernel<<<((NNODE + 1) * 32 + 255) / 256, 256, 0, stream>>>(
        embed_user, embed_item, wout, b1tab, b2tab, f1tab, f2tab);

    const int GNNB = (NNODE + 63) / 64;   // 2254
    gnn_layer_kernel<false><<<GNNB, 256, 0, stream>>>(
        f1tab, b1tab, row_ptr, csr_col, nullptr, sback, dinv, wout,
        W1, b1, Wi1, bi1, b2tab, f2tab);
    const int TGTB = (3 * B + 63) / 64;   // 384
    gnn_layer_kernel<true><<<TGTB, 256, 0, stream>>>(
        f2tab, b2tab, row_ptr, csr_col, tgt, sback, dinv, wout,
        W2, b2, Wi2, bi2, b3tab, nullptr);

    init_loss_kernel<<<1, 64, 0, stream>>>(out, 2 * B);
    const int SCORE_BLOCKS = 256;                      // 1024 waves, 8 samples each
    score_kernel<<<SCORE_BLOCKS, 256, 0, stream>>>(
        user, item_i, item_j, embed_user, embed_item, b2tab, b3tab, sback,
        out, B, SCORE_BLOCKS * 4);
}